// Round 1
// baseline (578.508 us; speedup 1.0000x reference)
//
#include <hip/hip_runtime.h>
#include <stdint.h>

// One block per 32-bit word. 4 waves/block; wave w handles byte position w.
// Each lane reads a float4 from a_bytes and b_bytes (coalesced), computes the
// one-hot index via a sum reduction Σ j*x[j] across the 64-lane wave, then the
// block computes s=(a+b) and out=s^a as uint32 and writes the one-hot result.
__global__ __launch_bounds__(256) void vm_kernel(
    const float* __restrict__ a_bytes,
    const float* __restrict__ b_bytes,
    float* __restrict__ out)
{
    const int word     = blockIdx.x;
    const int t        = threadIdx.x;
    const int byte_pos = t >> 6;   // wave index 0..3 == byte position
    const int lane     = t & 63;
    const long base = (long)word * 1024 + byte_pos * 256 + lane * 4;

    const float4 av = *(const float4*)(a_bytes + base);
    const float4 bv = *(const float4*)(b_bytes + base);

    // index = Σ j * x[j]  (x is exactly one-hot 0/1)
    const float j0 = (float)(lane * 4);
    float pa = av.x * j0 + av.y * (j0 + 1.0f) + av.z * (j0 + 2.0f) + av.w * (j0 + 3.0f);
    float pb = bv.x * j0 + bv.y * (j0 + 1.0f) + bv.z * (j0 + 2.0f) + bv.w * (j0 + 3.0f);
#pragma unroll
    for (int off = 32; off >= 1; off >>= 1) {
        pa += __shfl_xor(pa, off, 64);
        pb += __shfl_xor(pb, off, 64);
    }

    __shared__ int a_idx[4];
    __shared__ int b_idx[4];
    __shared__ int out_idx[4];
    if (lane == 0) {
        a_idx[byte_pos] = (int)(pa + 0.5f);
        b_idx[byte_pos] = (int)(pb + 0.5f);
    }
    __syncthreads();
    if (t == 0) {
        uint32_t aw = (uint32_t)a_idx[0] | ((uint32_t)a_idx[1] << 8) |
                      ((uint32_t)a_idx[2] << 16) | ((uint32_t)a_idx[3] << 24);
        uint32_t bw = (uint32_t)b_idx[0] | ((uint32_t)b_idx[1] << 8) |
                      ((uint32_t)b_idx[2] << 16) | ((uint32_t)b_idx[3] << 24);
        uint32_t s = aw + bw;       // ripple-carry add, carry out of byte 3 dropped
        uint32_t o = s ^ aw;        // chained byte-wise XOR with operand a
        out_idx[0] = (int)(o & 255u);
        out_idx[1] = (int)((o >> 8) & 255u);
        out_idx[2] = (int)((o >> 16) & 255u);
        out_idx[3] = (int)((o >> 24) & 255u);
    }
    __syncthreads();

    const int oi = out_idx[byte_pos];
    const int j  = lane * 4;
    float4 ov;
    ov.x = (j     == oi) ? 1.0f : 0.0f;
    ov.y = (j + 1 == oi) ? 1.0f : 0.0f;
    ov.z = (j + 2 == oi) ? 1.0f : 0.0f;
    ov.w = (j + 3 == oi) ? 1.0f : 0.0f;
    *(float4*)(out + base) = ov;
}

extern "C" void kernel_launch(void* const* d_in, const int* in_sizes, int n_in,
                              void* d_out, int out_size, void* d_ws, size_t ws_size,
                              hipStream_t stream)
{
    const float* a_bytes = (const float*)d_in[0];  // [B,4,256]
    const float* b_bytes = (const float*)d_in[1];  // [B,4,256]
    float* out = (float*)d_out;                    // [B,4,256]
    const int n_words = in_sizes[0] / 1024;        // B
    vm_kernel<<<n_words, 256, 0, stream>>>(a_bytes, b_bytes, out);
}